// Round 1
// baseline (514.517 us; speedup 1.0000x reference)
//
#include <hip/hip_runtime.h>
#include <math.h>

// Problem constants (match reference)
#define BB 32
#define SS 2048
#define DD 1024
#define BETA_C 0.1f
#define RHO_C 1.0f

#define TPB 256
#define NBLK_PER_T 1024       // blocks per tensor; grid = 2048 (8 blocks/CU)
#define CHUNK_V4 16384        // float4 per block = 256 KB contiguous per block
// 32 blocks per 8 MiB batch row; chunk base ≡ 0 (mod 256 vec4) so each
// thread's w index is exactly threadIdx.x for every load.

__device__ __forceinline__ float dot4(float4 a, float4 b) {
    return a.x * b.x + a.y * b.y + a.z * b.z + a.w * b.w;
}

// lp[t*BB + b] = sum over e_t[b,:,:] * w (broadcast over S).
// Canonical peak-read stream (copy-bench shape): 2048 blocks x 256 threads,
// per-block contiguous 256 KB, thread-contiguous float4 loads (1 KB per wave
// instruction), 8 loads in flight, 8 accumulators, one w4 register per thread.
__global__ __launch_bounds__(TPB) void dot_kernel(
    const float* __restrict__ e1, const float* __restrict__ e2,
    const float* __restrict__ w, float* __restrict__ lp)
{
    const int t     = blockIdx.x >> 10;           // 0: e1, 1: e2
    const int j     = blockIdx.x & (NBLK_PER_T - 1);
    const int tid   = threadIdx.x;
    const int lane  = tid & 63;
    const int wid   = tid >> 6;
    const int batch = j >> 5;                     // 32 blocks per batch row

    const float4 wv = ((const float4*)w)[tid];    // vec_idx mod 256 == tid always
    const float4* p = (const float4*)(t ? e2 : e1)
                    + (long long)j * CHUNK_V4 + tid;

    float a0 = 0.f, a1 = 0.f, a2 = 0.f, a3 = 0.f;
    float a4 = 0.f, a5 = 0.f, a6 = 0.f, a7 = 0.f;
    #pragma unroll
    for (int k = 0; k < 64; k += 8) {
        const float4 v0 = p[(k + 0) * TPB];
        const float4 v1 = p[(k + 1) * TPB];
        const float4 v2 = p[(k + 2) * TPB];
        const float4 v3 = p[(k + 3) * TPB];
        const float4 v4 = p[(k + 4) * TPB];
        const float4 v5 = p[(k + 5) * TPB];
        const float4 v6 = p[(k + 6) * TPB];
        const float4 v7 = p[(k + 7) * TPB];
        a0 += dot4(v0, wv);
        a1 += dot4(v1, wv);
        a2 += dot4(v2, wv);
        a3 += dot4(v3, wv);
        a4 += dot4(v4, wv);
        a5 += dot4(v5, wv);
        a6 += dot4(v6, wv);
        a7 += dot4(v7, wv);
    }
    float s = ((a0 + a4) + (a1 + a5)) + ((a2 + a6) + (a3 + a7));

    // wave (64-lane) reduction
    #pragma unroll
    for (int off = 32; off > 0; off >>= 1)
        s += __shfl_down(s, off, 64);

    __shared__ float red[TPB / 64];
    if (lane == 0) red[wid] = s;
    __syncthreads();
    if (threadIdx.x == 0) {
        float tot = 0.f;
        #pragma unroll
        for (int i = 0; i < TPB / 64; i++) tot += red[i];
        atomicAdd(&lp[t * BB + batch], tot);   // 32 atomics per address
    }
}

__device__ __forceinline__ float log_sigmoid(float x) {
    // stable: min(x,0) - log1p(exp(-|x|))
    return fminf(x, 0.f) - log1pf(expf(-fabsf(x)));
}

// One wave: closed-form loss + grad-norm term.
// grad wrt embeddings is rank-1: g1[b,s,d] = beta*(sigma(z_b)-p_b)*w[d], g2 = -g1
// => grad_norm_sq[b] = 2*beta^2*(sigma(z_b)-p_b)^2 * S * sum(w^2)
__global__ void finalize_kernel(
    const float* __restrict__ lp, const float* __restrict__ w,
    const float* __restrict__ lp1ref, const float* __restrict__ lp2ref,
    const float* __restrict__ pref, float* __restrict__ out)
{
    const int lane = threadIdx.x;   // 64 threads
    float sw2 = 0.f;
    for (int i = lane; i < DD; i += 64) { const float x = w[i]; sw2 += x * x; }
    #pragma unroll
    for (int off = 32; off > 0; off >>= 1) sw2 += __shfl_down(sw2, off, 64);
    sw2 = __shfl(sw2, 0, 64);       // broadcast sum w^2

    float ind = 0.f, gns = 0.f;
    if (lane < BB) {
        const float z = BETA_C * ((lp[lane] - lp1ref[lane]) - (lp[BB + lane] - lp2ref[lane]));
        const float p = pref[lane];
        const float l1 = -log_sigmoid(z);
        const float l2 = -log_sigmoid(-z);
        ind = p * l1 + (1.f - p) * l2;
        const float sig = 1.f / (1.f + expf(-z));
        const float dv  = sig - p;                  // d(ind)/dz
        gns = 2.f * BETA_C * BETA_C * (float)SS * sw2 * dv * dv;
    }
    #pragma unroll
    for (int off = 32; off > 0; off >>= 1) {
        ind += __shfl_down(ind, off, 64);
        gns += __shfl_down(gns, off, 64);
    }
    if (lane == 0)
        out[0] = ind / (float)BB + RHO_C * sqrtf(gns / (float)BB);
}

extern "C" void kernel_launch(void* const* d_in, const int* in_sizes, int n_in,
                              void* d_out, int out_size, void* d_ws, size_t ws_size,
                              hipStream_t stream) {
    const float* e1     = (const float*)d_in[0];
    const float* e2     = (const float*)d_in[1];
    const float* w      = (const float*)d_in[2];
    const float* lp1ref = (const float*)d_in[3];
    const float* lp2ref = (const float*)d_in[4];
    const float* pref   = (const float*)d_in[5];
    float* out = (float*)d_out;
    float* lp  = (float*)d_ws;   // lp1[32] then lp2[32]

    hipMemsetAsync(lp, 0, 2 * BB * sizeof(float), stream);
    dot_kernel<<<2 * NBLK_PER_T, TPB, 0, stream>>>(e1, e2, w, lp);
    finalize_kernel<<<1, 64, 0, stream>>>(lp, w, lp1ref, lp2ref, pref, out);
}